// Round 5
// baseline (34.872 us; speedup 1.0000x reference)
//
#include <hip/hip_runtime.h>
#include <hip/hip_bf16.h>
#include <math.h>

#define BB 8
#define SS 2048
#define HH 768
#define NN 512
#define MAXW 30
#define CK 6          // rows per chunk

// ---- Kernel A: per-example counting sort of spans by start (parallel scan) ----
__global__ __launch_bounds__(256) void sort_spans_kernel(
    const int* __restrict__ starts,   // (B, N)
    int*       __restrict__ order)    // (B, N): order[b*N + rank] = span idx
{
    const int b   = blockIdx.x;
    const int tid = threadIdx.x;
    __shared__ int hist[SS];
    __shared__ int wsum[4];

    for (int i = tid; i < SS; i += 256) hist[i] = 0;
    __syncthreads();

    const int* st = starts + b * NN;
    for (int n = tid; n < NN; n += 256) atomicAdd(&hist[st[n]], 1);
    __syncthreads();

    const int base = tid * 8;
    int cnt[8]; int s = 0;
    #pragma unroll
    for (int k = 0; k < 8; ++k) { cnt[k] = hist[base + k]; s += cnt[k]; }

    const int lane = tid & 63, wv = tid >> 6;
    int v = s;
    #pragma unroll
    for (int off = 1; off < 64; off <<= 1) {
        int u = __shfl_up(v, off);
        if (lane >= off) v += u;
    }
    if (lane == 63) wsum[wv] = v;
    __syncthreads();
    int wbase = 0;
    #pragma unroll
    for (int k = 0; k < 4; ++k) wbase += (k < wv) ? wsum[k] : 0;

    int excl = wbase + v - s;
    #pragma unroll
    for (int k = 0; k < 8; ++k) { int c = cnt[k]; hist[base + k] = excl; excl += c; }
    __syncthreads();

    for (int n = tid; n < NN; n += 256) {
        int pos = atomicAdd(&hist[st[n]], 1);
        order[b * NN + pos] = n;
    }
}

// ---- Kernel B: fused single-pass span kernel, chunked (CK rows at a time).
//      One wave per span; online softmax with one rescale per chunk;
//      interleaved butterfly reduces for ILP. No LDS, no __syncthreads.
__global__ __launch_bounds__(256) void span_fused_kernel(
    const float* __restrict__ emb,      // (B, S, H)
    const float* __restrict__ w,        // (H)
    const float* __restrict__ bias,     // (1)
    const int*   __restrict__ starts,   // (B, N)
    const int*   __restrict__ lengths,  // (B, N)
    const int*   __restrict__ order,    // (B, N) or nullptr
    float*       __restrict__ out)      // (B, N, 3H)
{
    const int tid  = threadIdx.x;
    const int wv   = tid >> 6;
    const int lane = tid & 63;
    const int bi   = blockIdx.x & 7;                 // example <-> XCD
    const int rank = ((int)blockIdx.x >> 3) * 4 + wv;
    const int n    = order ? order[bi * NN + rank] : rank;
    const int span = bi * NN + n;

    const int start = starts[span];
    const int len   = lengths[span];                 // valid t = 0..len (<= 29)

    const float* ebase = emb + (size_t)bi * SS * HH + (size_t)start * HH;
    const int h0 = lane * 4;
    float* orow = out + (size_t)span * (3 * HH);

    const float4 w0 = *reinterpret_cast<const float4*>(w + h0);
    const float4 w1 = *reinterpret_cast<const float4*>(w + h0 + 256);
    const float4 w2 = *reinterpret_cast<const float4*>(w + h0 + 512);
    const float bb = bias[0];

    float m = -INFINITY, ssum = 0.f;
    float4 a0 = make_float4(0.f, 0.f, 0.f, 0.f), a1 = a0, a2 = a0;

    const int nchunks = (len + CK) / CK;             // ceil((len+1)/CK), 1..5

    for (int c = 0; c < nchunks; ++c) {
        const int tbase = c * CK;

        // ---- load CK rows (all loads issued together; OOB-in-chunk rows are
        //      provably in-bounds: start <= S-MAXW-1, tbase+k <= 29) ----
        float4 r0[CK], r1[CK], r2[CK];
        #pragma unroll
        for (int k = 0; k < CK; ++k) {
            const float* rp = ebase + (size_t)(tbase + k) * HH;
            r0[k] = *reinterpret_cast<const float4*>(rp + h0);
            r1[k] = *reinterpret_cast<const float4*>(rp + h0 + 256);
            r2[k] = *reinterpret_cast<const float4*>(rp + h0 + 512);
        }

        // ---- per-lane partial dots (independent chains) ----
        float d[CK];
        #pragma unroll
        for (int k = 0; k < CK; ++k) {
            d[k] = r0[k].x * w0.x + r0[k].y * w0.y + r0[k].z * w0.z + r0[k].w * w0.w
                 + r1[k].x * w1.x + r1[k].y * w1.y + r1[k].z * w1.z + r1[k].w * w1.w
                 + r2[k].x * w2.x + r2[k].y * w2.y + r2[k].z * w2.z + r2[k].w * w2.w;
        }

        // ---- interleaved butterfly reduces (CK independent chains) ----
        #pragma unroll
        for (int off = 32; off; off >>= 1) {
            #pragma unroll
            for (int k = 0; k < CK; ++k) d[k] += __shfl_xor(d[k], off);
        }

        // ---- bias + mask ----
        #pragma unroll
        for (int k = 0; k < CK; ++k)
            d[k] = (tbase + k <= len) ? (d[k] + bb) : -INFINITY;

        // ---- one rescale per chunk ----
        float cmax = d[0];
        #pragma unroll
        for (int k = 1; k < CK; ++k) cmax = fmaxf(cmax, d[k]);
        if (cmax > m) {
            const float cc = __expf(m - cmax);       // chunk 0: exp(-inf)=0
            ssum *= cc;
            a0.x *= cc; a0.y *= cc; a0.z *= cc; a0.w *= cc;
            a1.x *= cc; a1.y *= cc; a1.z *= cc; a1.w *= cc;
            a2.x *= cc; a2.y *= cc; a2.z *= cc; a2.w *= cc;
            m = cmax;
        }

        // ---- weighted accumulate + start/end row emission ----
        #pragma unroll
        for (int k = 0; k < CK; ++k) {
            const float pt = __expf(d[k] - m);       // masked rows -> 0
            ssum += pt;
            a0.x += pt * r0[k].x; a0.y += pt * r0[k].y; a0.z += pt * r0[k].z; a0.w += pt * r0[k].w;
            a1.x += pt * r1[k].x; a1.y += pt * r1[k].y; a1.z += pt * r1[k].z; a1.w += pt * r1[k].w;
            a2.x += pt * r2[k].x; a2.y += pt * r2[k].y; a2.z += pt * r2[k].z; a2.w += pt * r2[k].w;

            if (tbase + k == 0) {                    // start row
                *reinterpret_cast<float4*>(orow + h0)       = r0[k];
                *reinterpret_cast<float4*>(orow + h0 + 256) = r1[k];
                *reinterpret_cast<float4*>(orow + h0 + 512) = r2[k];
            }
            if (tbase + k == len) {                  // end row
                *reinterpret_cast<float4*>(orow + HH + h0)       = r0[k];
                *reinterpret_cast<float4*>(orow + HH + h0 + 256) = r1[k];
                *reinterpret_cast<float4*>(orow + HH + h0 + 512) = r2[k];
            }
        }
    }

    const float inv = 1.f / ssum;
    a0.x *= inv; a0.y *= inv; a0.z *= inv; a0.w *= inv;
    a1.x *= inv; a1.y *= inv; a1.z *= inv; a1.w *= inv;
    a2.x *= inv; a2.y *= inv; a2.z *= inv; a2.w *= inv;
    *reinterpret_cast<float4*>(orow + 2 * HH + h0)       = a0;
    *reinterpret_cast<float4*>(orow + 2 * HH + h0 + 256) = a1;
    *reinterpret_cast<float4*>(orow + 2 * HH + h0 + 512) = a2;
}

extern "C" void kernel_launch(void* const* d_in, const int* in_sizes, int n_in,
                              void* d_out, int out_size, void* d_ws, size_t ws_size,
                              hipStream_t stream) {
    const float* emb     = (const float*)d_in[0];
    const float* w       = (const float*)d_in[1];
    const float* bias    = (const float*)d_in[2];
    const int*   starts  = (const int*)d_in[3];
    const int*   lengths = (const int*)d_in[4];
    float*       out     = (float*)d_out;

    int* order = nullptr;
    if (ws_size >= (size_t)(BB * NN * sizeof(int))) {
        order = (int*)d_ws;
        sort_spans_kernel<<<dim3(BB), dim3(256), 0, stream>>>(starts, order);
    }

    span_fused_kernel<<<dim3(BB * NN / 4), dim3(256), 0, stream>>>(
        emb, w, bias, starts, lengths, order, out);
}